// Round 7
// baseline (3782.995 us; speedup 1.0000x reference)
//
#include <hip/hip_runtime.h>
#include <hip/hip_bf16.h>

#define N_SENT 2048
#define S_LEN  64
#define QL     16
#define NQ     128
#define NB     32
#define DD     256
#define VOCAB  100032

#define NCH  8          // chains per workgroup (scan)
#define PADC 264        // padded A-array row length (u16) -> 4c bank skew

using bf16x8 = __attribute__((ext_vector_type(8))) short;
using f32x4  = __attribute__((ext_vector_type(4))) float;

// ---------------- workspace layout (float offsets) ----------------
#define WS_X   0
#define WS_WX  (WS_X  + N_SENT*DD)
#define WS_Q   (WS_WX + N_SENT*DD)
#define WS_KS  (WS_Q  + NQ*DD)
#define WS_KVB (WS_KS + N_SENT*NB)
#define WS_HF  (WS_KVB+ NB*DD)
#define WS_Z   (WS_HF + NB*DD)
#define WS_BF  (WS_Z  + NQ*DD)        // 131072 ushort

// ---------------- encoders ----------------
__global__ __launch_bounds__(256) void encode_story(
    const int* __restrict__ inp, const float* __restrict__ emb,
    const float* __restrict__ f, float* __restrict__ X)
{
    const int t = blockIdx.x, d = threadIdx.x;
    __shared__ int idx[S_LEN];
    if (d < S_LEN) idx[d] = inp[t*S_LEN + d];
    __syncthreads();
    float acc = 0.f;
#pragma unroll 4
    for (int p = 0; p < S_LEN; ++p)
        acc += emb[(size_t)idx[p]*DD + d] * f[p*DD + d];
    X[t*DD + d] = acc;
}

__global__ __launch_bounds__(256) void encode_query(
    const int* __restrict__ qry, const float* __restrict__ emb,
    const float* __restrict__ f, float* __restrict__ Q)
{
    const int i = blockIdx.x, d = threadIdx.x;
    __shared__ int idx[QL];
    if (d < QL) idx[d] = qry[i*QL + d];
    __syncthreads();
    float acc = 0.f;
#pragma unroll
    for (int p = 0; p < QL; ++p)
        acc += emb[(size_t)idx[p]*DD + d] * f[p*DD + d];
    Q[i*DD + d] = acc;
}

// ---------------- WX / KS ----------------
__global__ __launch_bounds__(256) void wx_ks(
    const float* __restrict__ X, const float* __restrict__ W,
    const float* __restrict__ keys, float* __restrict__ WX, float* __restrict__ KS)
{
    const int t = blockIdx.x, n = threadIdx.x;
    __shared__ float xs[DD];
    xs[n] = X[t*DD + n];
    __syncthreads();
    float acc = 0.f;
    const float4* wr = (const float4*)&W[n*DD];
    const float4* xp = (const float4*)xs;
#pragma unroll 8
    for (int k4 = 0; k4 < 64; ++k4) {
        float4 w = wr[k4], x = xp[k4];
        acc += w.x*x.x + w.y*x.y + w.z*x.z + w.w*x.w;
    }
    WX[t*DD + n] = acc;
    if (n < NB) {
        float a2 = 0.f;
        const float4* kr = (const float4*)&keys[n*DD];
#pragma unroll 8
        for (int k4 = 0; k4 < 64; ++k4) {
            float4 kv = kr[k4], x = xp[k4];
            a2 += kv.x*x.x + kv.y*x.y + kv.z*x.z + kv.w*x.w;
        }
        KS[t*NB + n] = a2;
    }
}

// ---------------- KVB ----------------
__global__ __launch_bounds__(256) void kvb_kernel(
    const float* __restrict__ keys, const float* __restrict__ V,
    const float* __restrict__ bias, float* __restrict__ KVB)
{
    const int jj = blockIdx.x, n = threadIdx.x;
    __shared__ float ks[DD];
    ks[n] = keys[jj*DD + n];
    __syncthreads();
    float acc = bias[n];
    const float4* vr = (const float4*)&V[n*DD];
    const float4* kp = (const float4*)ks;
#pragma unroll 8
    for (int k4 = 0; k4 < 64; ++k4) {
        float4 v = vr[k4], k = kp[k4];
        acc += v.x*k.x + v.y*k.y + v.z*k.z + v.w*k.w;
    }
    KVB[jj*DD + n] = acc;
}

// ---------------- prep: U -> bf16 hi/lo MFMA B-fragments ----------------
// frag f = (pass*16 + ntile)*8 + ktile; lane l: B[k][n] = U[n][k],
// n = ntile*16 + (l&15), k = ktile*32 + (l>>4)*8 + i.
__global__ __launch_bounds__(64) void prep_ufrag(
    const float* __restrict__ U, ushort* __restrict__ Bf)
{
    const int f = blockIdx.x;         // 0..255
    const int l = threadIdx.x;        // 0..63
    const int kt = f & 7, nt = (f >> 3) & 15, p = f >> 7;
    const int n  = nt*16 + (l & 15);
    const int kb = kt*32 + (l >> 4)*8;
    ushort out[8];
#pragma unroll
    for (int i = 0; i < 8; ++i) {
        float v = U[n*DD + kb + i];
        unsigned b  = __float_as_uint(v);
        unsigned hi = b & 0xFFFF0000u;
        if (p == 0) out[i] = (ushort)(hi >> 16);
        else {
            float lo = v - __uint_as_float(hi);
            out[i] = (ushort)(__float_as_uint(lo) >> 16);
        }
    }
    *(uint4*)&Bf[((size_t)f*64 + l)*8] = *(const uint4*)out;
}

__device__ __forceinline__ void split_hilo(float v, ushort& hi, ushort& lo)
{
    unsigned b = __float_as_uint(v);
    unsigned h = b & 0xFFFF0000u;
    hi = (ushort)(h >> 16);
    lo = (ushort)(__float_as_uint(v - __uint_as_float(h)) >> 16);
}

// DPP helpers (VALU-pipe cross-lane, no LDS traffic)
#define DPP_ADD_F(x, ctrl) \
    ((x) + __int_as_float(__builtin_amdgcn_update_dpp(0, __float_as_int(x), (ctrl), 0xF, 0xF, true)))

__device__ __forceinline__ float red16(float x) {   // sum over 16-lane group
    x = DPP_ADD_F(x, 0xB1);    // quad_perm(1,0,3,2)  = xor1
    x = DPP_ADD_F(x, 0x4E);    // quad_perm(2,3,0,1)  = xor2
    x = DPP_ADD_F(x, 0x141);   // row_half_mirror     (pairs 8-groups)
    x = DPP_ADD_F(x, 0x140);   // row_mirror          (pairs 16-group)
    return x;
}
__device__ __forceinline__ int dpp_xor1_i(int v) {
    return __builtin_amdgcn_update_dpp(0, v, 0xB1, 0xF, 0xF, true);
}

// ---------------- sequential scan: 8-chain M=16 MFMA, 4 waves ----------------
// 4 workgroups x 8 chains. A = [16 rows = 8 chains x (hi,lo)] x K=256 of the
// UNNORMALIZED state h-hat; B = U hi/lo fragments (AGPR-resident). Wave w owns
// N-tiles 4w..4w+3; its lanes keep h-hat for (2 chains x 4 cols) in REGISTERS.
// Norm/gate reductions via DPP (VALU). X/WX/KS per-lane L2 loads, prefetched
// one step ahead. One barrier/step; A-arrays + pred double-buffered.
__global__ __launch_bounds__(256)
__attribute__((amdgpu_waves_per_eu(1, 1)))
void scan_kernel(
    const float* __restrict__ X,  const float* __restrict__ WX,
    const float* __restrict__ KS, const float* __restrict__ KVB,
    const ushort* __restrict__ Bf, const float* __restrict__ h0,
    const float* __restrict__ a_mem_p, float* __restrict__ Hf,
    float* __restrict__ HfOut)
{
    const int j0   = blockIdx.x * NCH;
    const int tid  = threadIdx.x;
    const int w    = tid >> 6;        // wave 0..3
    const int lane = tid & 63;
    const int c15  = lane & 15;
    const int g    = lane >> 4;       // 0..3
    const int ca   = 2*g, cb = 2*g + 1;          // this lane's two chains

    __shared__ __align__(16) ushort hhi[2][NCH][PADC];
    __shared__ __align__(16) ushort hlo[2][NCH][PADC];
    __shared__ __align__(16) float  pred[2][16][4];   // [buf][val][wave]

    // ---- B fragments (persist; MFMA reads from VGPR/AGPR natively) ----
    bf16x8 bH[4][8], bL[4][8];
#pragma unroll
    for (int i = 0; i < 4; ++i)
#pragma unroll
        for (int kt = 0; kt < 8; ++kt) {
            bH[i][kt] = *(const bf16x8*)&Bf[(((size_t)(0*16 + 4*w + i)*8 + kt)*64 + lane)*8];
            bL[i][kt] = *(const bf16x8*)&Bf[(((size_t)(1*16 + 4*w + i)*8 + kt)*64 + lane)*8];
        }

    const float am = *a_mem_p;
    int col[4];
#pragma unroll
    for (int i = 0; i < 4; ++i) col[i] = 64*w + 16*i + c15;

    // ---- init: state + KVB in regs, A-arrays buf0, pred0 ----
    float hA[4], hB[4], kvA[4], kvB[4];
    float gsA_p = 0.f, gsB_p = 0.f;
#pragma unroll
    for (int i = 0; i < 4; ++i) {
        hA[i]  = h0[(j0 + ca)*DD + col[i]];
        hB[i]  = h0[(j0 + cb)*DD + col[i]];
        kvA[i] = KVB[(j0 + ca)*DD + col[i]];
        kvB[i] = KVB[(j0 + cb)*DD + col[i]];
        float x0 = X[col[i]];
        gsA_p += hA[i]*x0;  gsB_p += hB[i]*x0;
        ushort hh, hl;
        split_hilo(hA[i], hh, hl); hhi[0][ca][col[i]] = hh; hlo[0][ca][col[i]] = hl;
        split_hilo(hB[i], hh, hl); hhi[0][cb][col[i]] = hh; hlo[0][cb][col[i]] = hl;
    }
    {   // pred[0]: ns forced so inv=1 (reference uses raw h0); gs = h0 . x0
        float gsA = red16(gsA_p), gsB = red16(gsB_p);
        float val = (c15 == 0) ? 0.25f : (c15 == 1) ? 0.25f : (c15 == 2) ? gsA : gsB;
        int   row = (c15 == 0) ? ca : (c15 == 1) ? cb : (c15 == 2) ? 8 + ca : 8 + cb;
        if (c15 < 4) pred[0][row][w] = val;
    }
    // prefetch t=0 consumables
    float wxc[4], ksA, ksB;
#pragma unroll
    for (int i = 0; i < 4; ++i) wxc[i] = WX[col[i]];
    ksA = KS[j0 + ca];  ksB = KS[j0 + cb];
    __syncthreads();

    int cur = 0;
    for (int t = 0; t < N_SENT; ++t) {
        const int nxt = cur ^ 1;
        // ---- prefetch t+1 (L2; consumed at epilogue, ~600 cyc later) ----
        const int tn = (t + 1 < N_SENT) ? t + 1 : t;
        float xn[4], wxn[4];
#pragma unroll
        for (int i = 0; i < 4; ++i) {
            xn[i]  = X [tn*DD + col[i]];
            wxn[i] = WX[tn*DD + col[i]];
        }
        const float ksnA = KS[tn*NB + j0 + ca];
        const float ksnB = KS[tn*NB + j0 + cb];

        // ---- inv + gate from pred[cur] ----
        float4 pA = *(const float4*)&pred[cur][ca][0];
        float4 pB = *(const float4*)&pred[cur][cb][0];
        float4 qA = *(const float4*)&pred[cur][8 + ca][0];
        float4 qB = *(const float4*)&pred[cur][8 + cb][0];
        const float invA = rsqrtf(pA.x + pA.y + pA.z + pA.w);
        const float invB = rsqrtf(pB.x + pB.y + pB.z + pB.w);
        const float gateA = 1.f / (1.f + expf(-(invA*(qA.x+qA.y+qA.z+qA.w) + ksA)));
        const float gateB = 1.f / (1.f + expf(-(invB*(qB.x+qB.y+qB.z+qB.w) + ksB)));

        // ---- A fragments: row c15 = chain (c15>>1), hi/lo by parity ----
        bf16x8 a[8];
        {
            const ushort* base = (c15 & 1) ? &hlo[cur][c15 >> 1][0] : &hhi[cur][c15 >> 1][0];
#pragma unroll
            for (int kt = 0; kt < 8; ++kt)
                a[kt] = *(const bf16x8*)&base[kt*32 + g*8];
        }

        // ---- MFMAs: 4 N-tiles x 2 passes x 8 K-tiles ----
        f32x4 aH0={0,0,0,0}, aH1={0,0,0,0}, aH2={0,0,0,0}, aH3={0,0,0,0};
        f32x4 aL0={0,0,0,0}, aL1={0,0,0,0}, aL2={0,0,0,0}, aL3={0,0,0,0};
#pragma unroll
        for (int kt = 0; kt < 8; ++kt) {
            aH0 = __builtin_amdgcn_mfma_f32_16x16x32_bf16(a[kt], bH[0][kt], aH0, 0, 0, 0);
            aH1 = __builtin_amdgcn_mfma_f32_16x16x32_bf16(a[kt], bH[1][kt], aH1, 0, 0, 0);
            aH2 = __builtin_amdgcn_mfma_f32_16x16x32_bf16(a[kt], bH[2][kt], aH2, 0, 0, 0);
            aH3 = __builtin_amdgcn_mfma_f32_16x16x32_bf16(a[kt], bH[3][kt], aH3, 0, 0, 0);
            aL0 = __builtin_amdgcn_mfma_f32_16x16x32_bf16(a[kt], bL[0][kt], aL0, 0, 0, 0);
            aL1 = __builtin_amdgcn_mfma_f32_16x16x32_bf16(a[kt], bL[1][kt], aL1, 0, 0, 0);
            aL2 = __builtin_amdgcn_mfma_f32_16x16x32_bf16(a[kt], bL[2][kt], aL2, 0, 0, 0);
            aL3 = __builtin_amdgcn_mfma_f32_16x16x32_bf16(a[kt], bL[3][kt], aL3, 0, 0, 0);
        }

        // ---- epilogue: y -> prelu -> hn; partials; pack+write A[nxt] ----
        float nsA = 0.f, nsB = 0.f;  gsA_p = 0.f; gsB_p = 0.f;
#pragma unroll
        for (int i = 0; i < 4; ++i) {
            const f32x4 aH = (i==0)?aH0:(i==1)?aH1:(i==2)?aH2:aH3;
            const f32x4 aL = (i==0)?aL0:(i==1)?aL1:(i==2)?aL2:aL3;
            // rows 4g..4g+3 = (ca hi, ca lo, cb hi, cb lo)
            float yA = invA*(aH[0] + aH[1] + aL[0]) + kvA[i] + wxc[i];
            float yB = invB*(aH[2] + aH[3] + aL[2]) + kvB[i] + wxc[i];
            float hsA = (yA >= 0.f) ? yA : am*yA;
            float hsB = (yB >= 0.f) ? yB : am*yB;
            float hnA = invA*hA[i] + gateA*hsA;
            float hnB = invB*hB[i] + gateB*hsB;
            hA[i] = hnA;  hB[i] = hnB;
            nsA += hnA*hnA;  nsB += hnB*hnB;
            gsA_p += hnA*xn[i];  gsB_p += hnB*xn[i];
            // split + lane-pair pack (2 cols per b32 write)
            ushort hiA, loA, hiB, loB;
            split_hilo(hnA, hiA, loA);  split_hilo(hnB, hiB, loB);
            int hiA_sw = dpp_xor1_i((int)hiA), loA_sw = dpp_xor1_i((int)loA);
            int hiB_sw = dpp_xor1_i((int)hiB), loB_sw = dpp_xor1_i((int)loB);
            const int colp = 32*w + 8*i + (c15 >> 1);
            if (!(c15 & 1)) {     // even lane: hi-array, low half = own col
                ((uint*)&hhi[nxt][ca][0])[colp] = (uint)hiA | ((uint)hiA_sw << 16);
                ((uint*)&hhi[nxt][cb][0])[colp] = (uint)hiB | ((uint)hiB_sw << 16);
            } else {              // odd lane: lo-array, low half = partner col
                ((uint*)&hlo[nxt][ca][0])[colp] = (uint)(ushort)loA_sw | ((uint)loA << 16);
                ((uint*)&hlo[nxt][cb][0])[colp] = (uint)(ushort)loB_sw | ((uint)loB << 16);
            }
        }
        // ---- cross-lane partial sums (DPP) + pred[nxt] ----
        {
            float rnsA = red16(nsA),  rnsB = red16(nsB);
            float rgsA = red16(gsA_p), rgsB = red16(gsB_p);
            float val = (c15 == 0) ? rnsA : (c15 == 1) ? rnsB : (c15 == 2) ? rgsA : rgsB;
            int   row = (c15 == 0) ? ca : (c15 == 1) ? cb : (c15 == 2) ? 8 + ca : 8 + cb;
            if (c15 < 4) pred[nxt][row][w] = val;
        }
#pragma unroll
        for (int i = 0; i < 4; ++i) wxc[i] = wxn[i];
        ksA = ksnA;  ksB = ksnB;
        cur = nxt;
        __syncthreads();
    }

    // ---- final normalize + output ----
    {
        float4 pA = *(const float4*)&pred[cur][ca][0];
        float4 pB = *(const float4*)&pred[cur][cb][0];
        const float invA = rsqrtf(pA.x + pA.y + pA.z + pA.w);
        const float invB = rsqrtf(pB.x + pB.y + pB.z + pB.w);
#pragma unroll
        for (int i = 0; i < 4; ++i) {
            float va = hA[i]*invA, vb = hB[i]*invB;
            Hf[(j0 + ca)*DD + col[i]]    = va;
            Hf[(j0 + cb)*DD + col[i]]    = vb;
            HfOut[(j0 + ca)*DD + col[i]] = va;
            HfOut[(j0 + cb)*DD + col[i]] = vb;
        }
    }
}

// ---------------- output module small part ----------------
__global__ __launch_bounds__(256) void out_small(
    const float* __restrict__ Qe, const float* __restrict__ Hfm,
    const float* __restrict__ Hw, const float* __restrict__ Hb,
    const float* __restrict__ a_out_p, float* __restrict__ Z)
{
    const int i = blockIdx.x, d = threadIdx.x;
    __shared__ float hsh[NB*DD];
    __shared__ float red[4];
    __shared__ float csh[NB];
    __shared__ float ush[DD];
#pragma unroll
    for (int jj = 0; jj < NB; ++jj) hsh[jj*DD + d] = Hfm[jj*DD + d];
    const float qd = Qe[i*DD + d];
    __syncthreads();
    float s2 = 0.f;
#pragma unroll
    for (int jj = 0; jj < NB; ++jj) { float h = hsh[jj*DD + d]; s2 += h*h; }
    for (int jj = 0; jj < NB; ++jj) {
        float p = qd * hsh[jj*DD + d];
        float m = p;
#pragma unroll
        for (int o = 32; o; o >>= 1) m = fmaxf(m, __shfl_xor(m, o));
        if ((d & 63) == 0) red[d >> 6] = m;
        __syncthreads();
        m = fmaxf(fmaxf(red[0], red[1]), fmaxf(red[2], red[3]));
        __syncthreads();
        float e = expf(p - m);
#pragma unroll
        for (int o = 32; o; o >>= 1) e += __shfl_xor(e, o);
        if ((d & 63) == 0) red[d >> 6] = e;
        __syncthreads();
        if (d == 0) csh[jj] = m + logf(red[0] + red[1] + red[2] + red[3]);
        __syncthreads();
    }
    float u = qd * s2;
#pragma unroll
    for (int jj = 0; jj < NB; ++jj) u -= csh[jj] * hsh[jj*DD + d];
    ush[d] = u;
    __syncthreads();
    float acc = qd + Hb[d];
    const float4* hwr = (const float4*)&Hw[d*DD];
    const float4* up  = (const float4*)ush;
#pragma unroll 8
    for (int k4 = 0; k4 < 64; ++k4) {
        float4 w = hwr[k4], uu = up[k4];
        acc += w.x*uu.x + w.y*uu.y + w.z*uu.z + w.w*uu.w;
    }
    const float ao = *a_out_p;
    Z[i*DD + d] = (acc >= 0.f) ? acc : ao * acc;
}

// ---------------- big GEMM: Y = Z @ Rw^T + Rb ----------------
__global__ __launch_bounds__(256) void out_gemm(
    const float* __restrict__ Z, const float* __restrict__ Rw,
    const float* __restrict__ Rb, float* __restrict__ Y)
{
    const int vt  = blockIdx.x * 64;
    const int tid = threadIdx.x;
    __shared__ float rw_sh[64*DD];
    __shared__ float z_sh[64*DD];
#pragma unroll
    for (int it = 0; it < 16; ++it) {
        int f = tid + it*256;
        int row = f >> 6, c = f & 63;
        float4 v = *(const float4*)&Rw[(size_t)(vt + row)*DD + 4*c];
        int u = c ^ ((row >> 2) & 7);
        *(float4*)&rw_sh[row*DD + 4*u] = v;
    }
    const int vg = tid & 15;
    const int ig = tid >> 4;
    const float4 rb4 = *(const float4*)&Rb[vt + vg*4];

    for (int ic = 0; ic < 2; ++ic) {
        const int i0 = ic * 64;
        __syncthreads();
#pragma unroll
        for (int it = 0; it < 16; ++it) {
            int f = tid + it*256;
            int row = f >> 6, c = f & 63;
            float4 v = *(const float4*)&Z[(i0 + row)*DD + 4*c];
            int u = c ^ ((row >> 2) & 7);
            *(float4*)&z_sh[row*DD + 4*u] = v;
        }
        __syncthreads();
        float acc[4][4];
#pragma unroll
        for (int b = 0; b < 4; ++b)
#pragma unroll
            for (int a = 0; a < 4; ++a) acc[b][a] = 0.f;
#pragma unroll 2
        for (int kc = 0; kc < 64; ++kc) {
            float4 ra[4], zb[4];
            const int ur = (kc ^ (vg & 7)) * 4;
            const int uz = (kc ^ (ig & 7)) * 4;
#pragma unroll
            for (int a = 0; a < 4; ++a) ra[a] = *(const float4*)&rw_sh[(vg*4 + a)*DD + ur];
#pragma unroll
            for (int b = 0; b < 4; ++b) zb[b] = *(const float4*)&z_sh[(ig*4 + b)*DD + uz];
#pragma unroll
            for (int b = 0; b < 4; ++b)
#pragma unroll
                for (int a = 0; a < 4; ++a)
                    acc[b][a] += zb[b].x*ra[a].x + zb[b].y*ra[a].y
                               + zb[b].z*ra[a].z + zb[b].w*ra[a].w;
        }
#pragma unroll
        for (int b = 0; b < 4; ++b) {
            int i = i0 + ig*4 + b;
            float4 o;
            o.x = acc[b][0] + rb4.x; o.y = acc[b][1] + rb4.y;
            o.z = acc[b][2] + rb4.z; o.w = acc[b][3] + rb4.w;
            *(float4*)&Y[(size_t)i*VOCAB + vt + vg*4] = o;
        }
    }
}

extern "C" void kernel_launch(void* const* d_in, const int* in_sizes, int n_in,
                              void* d_out, int out_size, void* d_ws, size_t ws_size,
                              hipStream_t stream)
{
    (void)in_sizes; (void)n_in; (void)out_size; (void)ws_size;
    const int*   inputs  = (const int*)  d_in[0];
    const int*   query   = (const int*)  d_in[1];
    const float* h0      = (const float*)d_in[2];
    const float* emb     = (const float*)d_in[3];
    const float* f_story = (const float*)d_in[4];
    const float* f_query = (const float*)d_in[5];
    const float* U       = (const float*)d_in[6];
    const float* V       = (const float*)d_in[7];
    const float* W       = (const float*)d_in[8];
    const float* bias    = (const float*)d_in[9];
    const float* keys    = (const float*)d_in[10];
    const float* a_mem   = (const float*)d_in[11];
    const float* Hw      = (const float*)d_in[12];
    const float* Hb      = (const float*)d_in[13];
    const float* Rw      = (const float*)d_in[14];
    const float* Rb      = (const float*)d_in[15];
    const float* a_out   = (const float*)d_in[16];

    float* ws  = (float*)d_ws;
    float* X   = ws + WS_X;
    float* WX  = ws + WS_WX;
    float* Qe  = ws + WS_Q;
    float* KS  = ws + WS_KS;
    float* KVB = ws + WS_KVB;
    float* Hf  = ws + WS_HF;
    float* Z   = ws + WS_Z;
    ushort* Bf = (ushort*)(ws + WS_BF);

    float* Y     = (float*)d_out;
    float* HfOut = Y + (size_t)NQ * VOCAB;

    encode_story<<<N_SENT, 256, 0, stream>>>(inputs, emb, f_story, X);
    encode_query<<<NQ,    256, 0, stream>>>(query,  emb, f_query, Qe);
    wx_ks      <<<N_SENT, 256, 0, stream>>>(X, W, keys, WX, KS);
    kvb_kernel <<<NB,     256, 0, stream>>>(keys, V, bias, KVB);
    prep_ufrag <<<256,     64, 0, stream>>>(U, Bf);
    scan_kernel<<<NB/NCH, 256, 0, stream>>>(X, WX, KS, KVB, Bf, h0, a_mem, Hf, HfOut);
    out_small  <<<NQ,     256, 0, stream>>>(Qe, Hf, Hw, Hb, a_out, Z);
    out_gemm   <<<VOCAB/64, 256, 0, stream>>>(Z, Rw, Rb, Y);
}

// Round 9
// 2692.630 us; speedup vs baseline: 1.4049x; 1.4049x over previous
//
#include <hip/hip_runtime.h>
#include <hip/hip_bf16.h>

#define N_SENT 2048
#define S_LEN  64
#define QL     16
#define NQ     128
#define NB     32
#define DD     256
#define VOCAB  100032

#define NCH  8          // chains per workgroup (scan)
#define PADC 264        // padded A row length (ushort): conflict-free b128 reads

using bf16x8 = __attribute__((ext_vector_type(8))) short;
using f32x4  = __attribute__((ext_vector_type(4))) float;
using i32x4  = __attribute__((ext_vector_type(4))) int;

// ---------------- workspace layout (float offsets) ----------------
#define WS_X   0
#define WS_WX  (WS_X  + N_SENT*DD)
#define WS_Q   (WS_WX + N_SENT*DD)
#define WS_KS  (WS_Q  + NQ*DD)
#define WS_KVB (WS_KS + N_SENT*NB)
#define WS_HF  (WS_KVB+ NB*DD)
#define WS_Z   (WS_HF + NB*DD)
#define WS_BF  (WS_Z  + NQ*DD)        // 131072 ushort

// ---------------- encoders ----------------
__global__ __launch_bounds__(256) void encode_story(
    const int* __restrict__ inp, const float* __restrict__ emb,
    const float* __restrict__ f, float* __restrict__ X)
{
    const int t = blockIdx.x, d = threadIdx.x;
    __shared__ int idx[S_LEN];
    if (d < S_LEN) idx[d] = inp[t*S_LEN + d];
    __syncthreads();
    float acc = 0.f;
#pragma unroll 4
    for (int p = 0; p < S_LEN; ++p)
        acc += emb[(size_t)idx[p]*DD + d] * f[p*DD + d];
    X[t*DD + d] = acc;
}

__global__ __launch_bounds__(256) void encode_query(
    const int* __restrict__ qry, const float* __restrict__ emb,
    const float* __restrict__ f, float* __restrict__ Q)
{
    const int i = blockIdx.x, d = threadIdx.x;
    __shared__ int idx[QL];
    if (d < QL) idx[d] = qry[i*QL + d];
    __syncthreads();
    float acc = 0.f;
#pragma unroll
    for (int p = 0; p < QL; ++p)
        acc += emb[(size_t)idx[p]*DD + d] * f[p*DD + d];
    Q[i*DD + d] = acc;
}

// ---------------- WX / KS ----------------
__global__ __launch_bounds__(256) void wx_ks(
    const float* __restrict__ X, const float* __restrict__ W,
    const float* __restrict__ keys, float* __restrict__ WX, float* __restrict__ KS)
{
    const int t = blockIdx.x, n = threadIdx.x;
    __shared__ float xs[DD];
    xs[n] = X[t*DD + n];
    __syncthreads();
    float acc = 0.f;
    const float4* wr = (const float4*)&W[n*DD];
    const float4* xp = (const float4*)xs;
#pragma unroll 8
    for (int k4 = 0; k4 < 64; ++k4) {
        float4 w = wr[k4], x = xp[k4];
        acc += w.x*x.x + w.y*x.y + w.z*x.z + w.w*x.w;
    }
    WX[t*DD + n] = acc;
    if (n < NB) {
        float a2 = 0.f;
        const float4* kr = (const float4*)&keys[n*DD];
#pragma unroll 8
        for (int k4 = 0; k4 < 64; ++k4) {
            float4 kv = kr[k4], x = xp[k4];
            a2 += kv.x*x.x + kv.y*x.y + kv.z*x.z + kv.w*x.w;
        }
        KS[t*NB + n] = a2;
    }
}

// ---------------- KVB ----------------
__global__ __launch_bounds__(256) void kvb_kernel(
    const float* __restrict__ keys, const float* __restrict__ V,
    const float* __restrict__ bias, float* __restrict__ KVB)
{
    const int jj = blockIdx.x, n = threadIdx.x;
    __shared__ float ks[DD];
    ks[n] = keys[jj*DD + n];
    __syncthreads();
    float acc = bias[n];
    const float4* vr = (const float4*)&V[n*DD];
    const float4* kp = (const float4*)ks;
#pragma unroll 8
    for (int k4 = 0; k4 < 64; ++k4) {
        float4 v = vr[k4], k = kp[k4];
        acc += v.x*k.x + v.y*k.y + v.z*k.z + v.w*k.w;
    }
    KVB[jj*DD + n] = acc;
}

// ---------------- prep: U -> bf16 hi/lo MFMA B-fragments ----------------
__global__ __launch_bounds__(64) void prep_ufrag(
    const float* __restrict__ U, ushort* __restrict__ Bf)
{
    const int f = blockIdx.x;         // 0..255
    const int l = threadIdx.x;        // 0..63
    const int kt = f & 7, nt = (f >> 3) & 15, p = f >> 7;
    const int n  = nt*16 + (l & 15);
    const int kb = kt*32 + (l >> 4)*8;
    ushort out[8];
#pragma unroll
    for (int i = 0; i < 8; ++i) {
        float v = U[n*DD + kb + i];
        unsigned b  = __float_as_uint(v);
        unsigned hi = b & 0xFFFF0000u;
        if (p == 0) out[i] = (ushort)(hi >> 16);
        else {
            float lo = v - __uint_as_float(hi);
            out[i] = (ushort)(__float_as_uint(lo) >> 16);
        }
    }
    *(uint4*)&Bf[((size_t)f*64 + l)*8] = *(const uint4*)out;
}

__device__ __forceinline__ void split_hilo(float v, ushort& hi, ushort& lo)
{
    unsigned b = __float_as_uint(v);
    unsigned h = b & 0xFFFF0000u;
    hi = (ushort)(h >> 16);
    lo = (ushort)(__float_as_uint(v - __uint_as_float(h)) >> 16);
}

template <int CTRL>
__device__ __forceinline__ int dpp_i(int v) {
    return __builtin_amdgcn_update_dpp(0, v, CTRL, 0xF, 0xF, true);
}
template <int CTRL>
__device__ __forceinline__ float dpp_f(float x) {
    return __int_as_float(dpp_i<CTRL>(__float_as_int(x)));
}

__device__ __forceinline__ float red16(float x) {   // sum over 16-lane group
    x += dpp_f<0xB1>(x);    // xor1 (quad_perm 1,0,3,2)
    x += dpp_f<0x4E>(x);    // xor2 (quad_perm 2,3,0,1)
    x += dpp_f<0x141>(x);   // row_half_mirror
    x += dpp_f<0x140>(x);   // row_mirror
    return x;
}

// ---------------- sequential scan ----------------
// 4 workgroups x 8 chains; A = [16 rows = 8 chains x (hi,lo)] x K=256 of the
// UNNORMALIZED h-hat in LDS (double-buffered). 8 waves (2/SIMD); wave w owns
// N-tiles {2w,2w+1}; B (Uhi+Ulo for both tiles) = 128 VGPR, persist. Pass-2
// A (hhi broadcast to both parity rows) derived from pass-1 A by one DPP
// quad_perm(0,0,2,2) -- no second LDS read. Norm/gate via per-(chain,wave)
// float2 partials + DPP reduce. One barrier/step.
__global__ __launch_bounds__(512)
__attribute__((amdgpu_waves_per_eu(2, 2)))
void scan_kernel(
    const float* __restrict__ X,  const float* __restrict__ WX,
    const float* __restrict__ KS, const float* __restrict__ KVB,
    const ushort* __restrict__ Bf, const float* __restrict__ h0,
    const float* __restrict__ a_mem_p, float* __restrict__ Hf,
    float* __restrict__ HfOut)
{
    const int j0   = blockIdx.x * NCH;
    const int tid  = threadIdx.x;
    const int w    = tid >> 6;        // wave 0..7
    const int lane = tid & 63;
    const int c15  = lane & 15;
    const int g    = lane >> 4;       // 0..3
    const int chA  = 2*g, chB = 2*g + 1;
    const bool oddl = (c15 & 1);

    __shared__ __align__(16) ushort arr[2][16][PADC];   // row = 2*chain+parity
    __shared__ float2 pred[2][NCH][8];                  // [buf][chain][wave] (ns,gs)

    // ---- B fragments [tile][pass][kt]  (32 x bf16x8 = 128 VGPR) ----
    bf16x8 bU[2][2][8];
#pragma unroll
    for (int tau = 0; tau < 2; ++tau)
#pragma unroll
        for (int p = 0; p < 2; ++p)
#pragma unroll
            for (int kt = 0; kt < 8; ++kt)
                bU[tau][p][kt] = *(const bf16x8*)
                    &Bf[(((size_t)(p*16 + 2*w + tau)*8 + kt)*64 + lane)*8];

    const float am = *a_mem_p;
    const int colt0 = 32*w + c15, colt1 = colt0 + 16;

    // ---- init state ----
    float hA[2], hB[2], kvA[2], kvB[2], wxc[2];
    float gsAi = 0.f, gsBi = 0.f;
#pragma unroll
    for (int tau = 0; tau < 2; ++tau) {
        const int ct = tau ? colt1 : colt0;
        hA[tau]  = h0[(j0 + chA)*DD + ct];
        hB[tau]  = h0[(j0 + chB)*DD + ct];
        kvA[tau] = KVB[(j0 + chA)*DD + ct];
        kvB[tau] = KVB[(j0 + chB)*DD + ct];
        wxc[tau] = WX[ct];
        float x0 = X[ct];
        gsAi += hA[tau]*x0;  gsBi += hB[tau]*x0;
        ushort hh, hl;
        split_hilo(hA[tau], hh, hl); arr[0][4*g+0][ct] = hh; arr[0][4*g+1][ct] = hl;
        split_hilo(hB[tau], hh, hl); arr[0][4*g+2][ct] = hh; arr[0][4*g+3][ct] = hl;
    }
    gsAi = red16(gsAi);  gsBi = red16(gsBi);
    if (c15 < 2)     // ns entries sum to 1 -> inv=1 at t=0 (reference uses raw h0)
        pred[0][chA + c15][w] = make_float2(0.125f, c15 ? gsBi : gsAi);
    float ksA = KS[j0 + chA], ksB = KS[j0 + chB];
    __syncthreads();

    int cur = 0;
    for (int t = 0; t < N_SENT; ++t) {
        const int nxt = cur ^ 1;
        const int tn  = (t + 1 < N_SENT) ? t + 1 : t;
        // ---- prefetch t+1 (consumed at epilogue / next step) ----
        float xn0  = X [tn*DD + colt0], xn1  = X [tn*DD + colt1];
        float wxn0 = WX[tn*DD + colt0], wxn1 = WX[tn*DD + colt1];
        float ksnA = KS[tn*NB + j0 + chA], ksnB = KS[tn*NB + j0 + chB];

        // ---- pred reduce: inv + gate for this step ----
        float2 pv = pred[cur][chA + (c15 >> 3)][c15 & 7];
        float rn = pv.x, rg = pv.y;
        rn += dpp_f<0xB1>(rn);   rg += dpp_f<0xB1>(rg);
        rn += dpp_f<0x4E>(rn);   rg += dpp_f<0x4E>(rg);
        rn += dpp_f<0x141>(rn);  rg += dpp_f<0x141>(rg);
        float rnO = dpp_f<0x140>(rn), rgO = dpp_f<0x140>(rg);
        const bool hiH = (c15 >= 8);
        float invA = rsqrtf(hiH ? rnO : rn);
        float invB = rsqrtf(hiH ? rn : rnO);
        float gA   = hiH ? rgO : rg;
        float gB   = hiH ? rg : rgO;
        float gateA = 1.f / (1.f + __expf(-(invA*gA + ksA)));
        float gateB = 1.f / (1.f + __expf(-(invB*gB + ksB)));

        // ---- A fragments (pass1: row c15; pass2 via quad_perm(0,0,2,2)) ----
        bf16x8 a1[8], a2[8];
#pragma unroll
        for (int kt = 0; kt < 8; ++kt)
            a1[kt] = *(const bf16x8*)&arr[cur][c15][kt*32 + g*8];
#pragma unroll
        for (int kt = 0; kt < 8; ++kt) {
            i32x4 u = __builtin_bit_cast(i32x4, a1[kt]);
            i32x4 v;
            v[0] = dpp_i<0xA0>(u[0]); v[1] = dpp_i<0xA0>(u[1]);
            v[2] = dpp_i<0xA0>(u[2]); v[3] = dpp_i<0xA0>(u[3]);
            a2[kt] = __builtin_bit_cast(bf16x8, v);
        }

        // ---- MFMAs: 2 tiles x 2 passes x 8 kt = 32 ----
        f32x4 p10 = {0,0,0,0}, p11 = {0,0,0,0}, p20 = {0,0,0,0}, p21 = {0,0,0,0};
#pragma unroll
        for (int kt = 0; kt < 8; ++kt) {
            p10 = __builtin_amdgcn_mfma_f32_16x16x32_bf16(a1[kt], bU[0][0][kt], p10, 0, 0, 0);
            p11 = __builtin_amdgcn_mfma_f32_16x16x32_bf16(a1[kt], bU[1][0][kt], p11, 0, 0, 0);
            p20 = __builtin_amdgcn_mfma_f32_16x16x32_bf16(a2[kt], bU[0][1][kt], p20, 0, 0, 0);
            p21 = __builtin_amdgcn_mfma_f32_16x16x32_bf16(a2[kt], bU[1][1][kt], p21, 0, 0, 0);
        }

        // ---- epilogue ----
        float nsAp = 0.f, nsBp = 0.f, gsAp = 0.f, gsBp = 0.f;
#pragma unroll
        for (int tau = 0; tau < 2; ++tau) {
            const f32x4 P1 = tau ? p11 : p10;
            const f32x4 P2 = tau ? p21 : p20;
            const float xnt = tau ? xn1 : xn0;
            float yA = invA*(P1[0] + P1[1] + P2[0]) + kvA[tau] + wxc[tau];
            float yB = invB*(P1[2] + P1[3] + P2[2]) + kvB[tau] + wxc[tau];
            float hsA = (yA >= 0.f) ? yA : am*yA;
            float hsB = (yB >= 0.f) ? yB : am*yB;
            float hnA = invA*hA[tau] + gateA*hsA;
            float hnB = invB*hB[tau] + gateB*hsB;
            hA[tau] = hnA;  hB[tau] = hnB;
            nsAp += hnA*hnA;  gsAp += hnA*xnt;
            nsBp += hnB*hnB;  gsBp += hnB*xnt;
            ushort hiA, loA, hiB, loB;
            split_hilo(hnA, hiA, loA);  split_hilo(hnB, hiB, loB);
            int hiAs = dpp_i<0xB1>((int)hiA), loAs = dpp_i<0xB1>((int)loA);
            int hiBs = dpp_i<0xB1>((int)hiB), loBs = dpp_i<0xB1>((int)loB);
            uint packH = oddl ? (((uint)(ushort)hiBs) | ((uint)hiB << 16))
                              : (((uint)hiA) | ((uint)(ushort)hiAs << 16));
            uint packL = oddl ? (((uint)(ushort)loBs) | ((uint)loB << 16))
                              : (((uint)loA) | ((uint)(ushort)loAs << 16));
            const int rowH = 4*g + (oddl ? 2 : 0);
            const int ucol = 16*w + 8*tau + (c15 >> 1);
            *((uint*)&arr[nxt][rowH][0]     + ucol) = packH;
            *((uint*)&arr[nxt][rowH + 1][0] + ucol) = packL;
        }
        nsAp = red16(nsAp);  gsAp = red16(gsAp);
        nsBp = red16(nsBp);  gsBp = red16(gsBp);
        if (c15 < 2)
            pred[nxt][chA + c15][w] = make_float2(c15 ? nsBp : nsAp,
                                                  c15 ? gsBp : gsAp);
        wxc[0] = wxn0;  wxc[1] = wxn1;  ksA = ksnA;  ksB = ksnB;
        cur = nxt;
        __syncthreads();
    }

    // ---- final normalize + output ----
    {
        float2 pv = pred[cur][chA + (c15 >> 3)][c15 & 7];
        float rn = pv.x;
        rn += dpp_f<0xB1>(rn); rn += dpp_f<0x4E>(rn); rn += dpp_f<0x141>(rn);
        float rnO = dpp_f<0x140>(rn);
        const bool hiH = (c15 >= 8);
        float invA = rsqrtf(hiH ? rnO : rn);
        float invB = rsqrtf(hiH ? rn : rnO);
#pragma unroll
        for (int tau = 0; tau < 2; ++tau) {
            const int ct = tau ? colt1 : colt0;
            float va = hA[tau]*invA, vb = hB[tau]*invB;
            Hf[(j0 + chA)*DD + ct]    = va;  Hf[(j0 + chB)*DD + ct]    = vb;
            HfOut[(j0 + chA)*DD + ct] = va;  HfOut[(j0 + chB)*DD + ct] = vb;
        }
    }
}

// ---------------- output module small part ----------------
__global__ __launch_bounds__(256) void out_small(
    const float* __restrict__ Qe, const float* __restrict__ Hfm,
    const float* __restrict__ Hw, const float* __restrict__ Hb,
    const float* __restrict__ a_out_p, float* __restrict__ Z)
{
    const int i = blockIdx.x, d = threadIdx.x;
    __shared__ float hsh[NB*DD];
    __shared__ float red[4];
    __shared__ float csh[NB];
    __shared__ float ush[DD];
#pragma unroll
    for (int jj = 0; jj < NB; ++jj) hsh[jj*DD + d] = Hfm[jj*DD + d];
    const float qd = Qe[i*DD + d];
    __syncthreads();
    float s2 = 0.f;
#pragma unroll
    for (int jj = 0; jj < NB; ++jj) { float h = hsh[jj*DD + d]; s2 += h*h; }
    for (int jj = 0; jj < NB; ++jj) {
        float p = qd * hsh[jj*DD + d];
        float m = p;
#pragma unroll
        for (int o = 32; o; o >>= 1) m = fmaxf(m, __shfl_xor(m, o));
        if ((d & 63) == 0) red[d >> 6] = m;
        __syncthreads();
        m = fmaxf(fmaxf(red[0], red[1]), fmaxf(red[2], red[3]));
        __syncthreads();
        float e = expf(p - m);
#pragma unroll
        for (int o = 32; o; o >>= 1) e += __shfl_xor(e, o);
        if ((d & 63) == 0) red[d >> 6] = e;
        __syncthreads();
        if (d == 0) csh[jj] = m + logf(red[0] + red[1] + red[2] + red[3]);
        __syncthreads();
    }
    float u = qd * s2;
#pragma unroll
    for (int jj = 0; jj < NB; ++jj) u -= csh[jj] * hsh[jj*DD + d];
    ush[d] = u;
    __syncthreads();
    float acc = qd + Hb[d];
    const float4* hwr = (const float4*)&Hw[d*DD];
    const float4* up  = (const float4*)ush;
#pragma unroll 8
    for (int k4 = 0; k4 < 64; ++k4) {
        float4 w = hwr[k4], uu = up[k4];
        acc += w.x*uu.x + w.y*uu.y + w.z*uu.z + w.w*uu.w;
    }
    const float ao = *a_out_p;
    Z[i*DD + d] = (acc >= 0.f) ? acc : ao * acc;
}

// ---------------- big GEMM: Y = Z @ Rw^T + Rb ----------------
__global__ __launch_bounds__(256) void out_gemm(
    const float* __restrict__ Z, const float* __restrict__ Rw,
    const float* __restrict__ Rb, float* __restrict__ Y)
{
    const int vt  = blockIdx.x * 64;
    const int tid = threadIdx.x;
    __shared__ float rw_sh[64*DD];
    __shared__ float z_sh[64*DD];
#pragma unroll
    for (int it = 0; it < 16; ++it) {
        int f = tid + it*256;
        int row = f >> 6, c = f & 63;
        float4 v = *(const float4*)&Rw[(size_t)(vt + row)*DD + 4*c];
        int u = c ^ ((row >> 2) & 7);
        *(float4*)&rw_sh[row*DD + 4*u] = v;
    }
    const int vg = tid & 15;
    const int ig = tid >> 4;
    const float4 rb4 = *(const float4*)&Rb[vt + vg*4];

    for (int ic = 0; ic < 2; ++ic) {
        const int i0 = ic * 64;
        __syncthreads();
#pragma unroll
        for (int it = 0; it < 16; ++it) {
            int f = tid + it*256;
            int row = f >> 6, c = f & 63;
            float4 v = *(const float4*)&Z[(i0 + row)*DD + 4*c];
            int u = c ^ ((row >> 2) & 7);
            *(float4*)&z_sh[row*DD + 4*u] = v;
        }
        __syncthreads();
        float acc[4][4];
#pragma unroll
        for (int b = 0; b < 4; ++b)
#pragma unroll
            for (int a = 0; a < 4; ++a) acc[b][a] = 0.f;
#pragma unroll 2
        for (int kc = 0; kc < 64; ++kc) {
            float4 ra[4], zb[4];
            const int ur = (kc ^ (vg & 7)) * 4;
            const int uz = (kc ^ (ig & 7)) * 4;
#pragma unroll
            for (int a = 0; a < 4; ++a) ra[a] = *(const float4*)&rw_sh[(vg*4 + a)*DD + ur];
#pragma unroll
            for (int b = 0; b < 4; ++b) zb[b] = *(const float4*)&z_sh[(ig*4 + b)*DD + uz];
#pragma unroll
            for (int b = 0; b < 4; ++b)
#pragma unroll
                for (int a = 0; a < 4; ++a)
                    acc[b][a] += zb[b].x*ra[a].x + zb[b].y*ra[a].y
                               + zb[b].z*ra[a].z + zb[b].w*ra[a].w;
        }
#pragma unroll
        for (int b = 0; b < 4; ++b) {
            int i = i0 + ig*4 + b;
            float4 o;
            o.x = acc[b][0] + rb4.x; o.y = acc[b][1] + rb4.y;
            o.z = acc[b][2] + rb4.z; o.w = acc[b][3] + rb4.w;
            *(float4*)&Y[(size_t)i*VOCAB + vt + vg*4] = o;
        }
    }
}

extern "C" void kernel_launch(void* const* d_in, const int* in_sizes, int n_in,
                              void* d_out, int out_size, void* d_ws, size_t ws_size,
                              hipStream_t stream)
{
    (void)in_sizes; (void)n_in; (void)out_size; (void)ws_size;
    const int*   inputs  = (const int*)  d_in[0];
    const int*   query   = (const int*)  d_in[1];
    const float* h0      = (const float*)d_in[2];
    const float* emb     = (const float*)d_in[3];
    const float* f_story = (const float*)d_in[4];
    const float* f_query = (const float*)d_in[5];
    const float* U       = (const float*)d_in[6];
    const float* V       = (const float*)d_in[7];
    const float* W       = (const float*)d_in[8];
    const float* bias    = (const float*)d_in[9];
    const float* keys    = (const float*)d_in[10];
    const float* a_mem   = (const float*)d_in[11];
    const float* Hw      = (const float*)d_in[12];
    const float* Hb      = (const float*)d_in[13];
    const float* Rw      = (const float*)d_in[14];
    const float* Rb      = (const float*)d_in[15];
    const float* a_out   = (const float*)d_in[16];

    float* ws  = (float*)d_ws;
    float* X   = ws + WS_X;
    float* WX  = ws + WS_WX;
    float* Qe  = ws + WS_Q;
    float* KS  = ws + WS_KS;
    float* KVB = ws + WS_KVB;
    float* Hf  = ws + WS_HF;
    float* Z   = ws + WS_Z;
    ushort* Bf = (ushort*)(ws + WS_BF);

    float* Y     = (float*)d_out;
    float* HfOut = Y + (size_t)NQ * VOCAB;

    encode_story<<<N_SENT, 256, 0, stream>>>(inputs, emb, f_story, X);
    encode_query<<<NQ,    256, 0, stream>>>(query,  emb, f_query, Qe);
    wx_ks      <<<N_SENT, 256, 0, stream>>>(X, W, keys, WX, KS);
    kvb_kernel <<<NB,     256, 0, stream>>>(keys, V, bias, KVB);
    prep_ufrag <<<256,     64, 0, stream>>>(U, Bf);
    scan_kernel<<<NB/NCH, 512, 0, stream>>>(X, WX, KS, KVB, Bf, h0, a_mem, Hf, HfOut);
    out_small  <<<NQ,     256, 0, stream>>>(Qe, Hf, Hw, Hb, a_out, Z);
    out_gemm   <<<VOCAB/64, 256, 0, stream>>>(Z, Rw, Rb, Y);
}

// Round 10
// 2519.748 us; speedup vs baseline: 1.5013x; 1.0686x over previous
//
#include <hip/hip_runtime.h>
#include <hip/hip_bf16.h>

#define N_SENT 2048
#define S_LEN  64
#define QL     16
#define NQ     128
#define NB     32
#define DD     256
#define VOCAB  100032

#define PADC 264        // A row length (ushort), 528B = 16B-aligned rows

using bf16x8 = __attribute__((ext_vector_type(8))) short;
using f32x4  = __attribute__((ext_vector_type(4))) float;

// ---------------- workspace layout (float offsets) ----------------
#define WS_X   0
#define WS_WX  (WS_X  + N_SENT*DD)
#define WS_Q   (WS_WX + N_SENT*DD)
#define WS_KS  (WS_Q  + NQ*DD)
#define WS_KVB (WS_KS + N_SENT*NB)
#define WS_HF  (WS_KVB+ NB*DD)
#define WS_Z   (WS_HF + NB*DD)
#define WS_BF  (WS_Z  + NQ*DD)        // 131072 ushort

// ---------------- encoders ----------------
__global__ __launch_bounds__(256) void encode_story(
    const int* __restrict__ inp, const float* __restrict__ emb,
    const float* __restrict__ f, float* __restrict__ X)
{
    const int t = blockIdx.x, d = threadIdx.x;
    __shared__ int idx[S_LEN];
    if (d < S_LEN) idx[d] = inp[t*S_LEN + d];
    __syncthreads();
    float acc = 0.f;
#pragma unroll 4
    for (int p = 0; p < S_LEN; ++p)
        acc += emb[(size_t)idx[p]*DD + d] * f[p*DD + d];
    X[t*DD + d] = acc;
}

__global__ __launch_bounds__(256) void encode_query(
    const int* __restrict__ qry, const float* __restrict__ emb,
    const float* __restrict__ f, float* __restrict__ Q)
{
    const int i = blockIdx.x, d = threadIdx.x;
    __shared__ int idx[QL];
    if (d < QL) idx[d] = qry[i*QL + d];
    __syncthreads();
    float acc = 0.f;
#pragma unroll
    for (int p = 0; p < QL; ++p)
        acc += emb[(size_t)idx[p]*DD + d] * f[p*DD + d];
    Q[i*DD + d] = acc;
}

// ---------------- WX / KS ----------------
__global__ __launch_bounds__(256) void wx_ks(
    const float* __restrict__ X, const float* __restrict__ W,
    const float* __restrict__ keys, float* __restrict__ WX, float* __restrict__ KS)
{
    const int t = blockIdx.x, n = threadIdx.x;
    __shared__ float xs[DD];
    xs[n] = X[t*DD + n];
    __syncthreads();
    float acc = 0.f;
    const float4* wr = (const float4*)&W[n*DD];
    const float4* xp = (const float4*)xs;
#pragma unroll 8
    for (int k4 = 0; k4 < 64; ++k4) {
        float4 w = wr[k4], x = xp[k4];
        acc += w.x*x.x + w.y*x.y + w.z*x.z + w.w*x.w;
    }
    WX[t*DD + n] = acc;
    if (n < NB) {
        float a2 = 0.f;
        const float4* kr = (const float4*)&keys[n*DD];
#pragma unroll 8
        for (int k4 = 0; k4 < 64; ++k4) {
            float4 kv = kr[k4], x = xp[k4];
            a2 += kv.x*x.x + kv.y*x.y + kv.z*x.z + kv.w*x.w;
        }
        KS[t*NB + n] = a2;
    }
}

// ---------------- KVB ----------------
__global__ __launch_bounds__(256) void kvb_kernel(
    const float* __restrict__ keys, const float* __restrict__ V,
    const float* __restrict__ bias, float* __restrict__ KVB)
{
    const int jj = blockIdx.x, n = threadIdx.x;
    __shared__ float ks[DD];
    ks[n] = keys[jj*DD + n];
    __syncthreads();
    float acc = bias[n];
    const float4* vr = (const float4*)&V[n*DD];
    const float4* kp = (const float4*)ks;
#pragma unroll 8
    for (int k4 = 0; k4 < 64; ++k4) {
        float4 v = vr[k4], k = kp[k4];
        acc += v.x*k.x + v.y*k.y + v.z*k.z + v.w*k.w;
    }
    KVB[jj*DD + n] = acc;
}

// ---------------- prep: U -> bf16 hi/lo MFMA B-fragments ----------------
__global__ __launch_bounds__(64) void prep_ufrag(
    const float* __restrict__ U, ushort* __restrict__ Bf)
{
    const int f = blockIdx.x;         // 0..255
    const int l = threadIdx.x;        // 0..63
    const int kt = f & 7, nt = (f >> 3) & 15, p = f >> 7;
    const int n  = nt*16 + (l & 15);
    const int kb = kt*32 + (l >> 4)*8;
    ushort out[8];
#pragma unroll
    for (int i = 0; i < 8; ++i) {
        float v = U[n*DD + kb + i];
        unsigned b  = __float_as_uint(v);
        unsigned hi = b & 0xFFFF0000u;
        if (p == 0) out[i] = (ushort)(hi >> 16);
        else {
            float lo = v - __uint_as_float(hi);
            out[i] = (ushort)(__float_as_uint(lo) >> 16);
        }
    }
    *(uint4*)&Bf[((size_t)f*64 + l)*8] = *(const uint4*)out;
}

__device__ __forceinline__ void split_hilo(float v, ushort& hi, ushort& lo)
{
    unsigned b = __float_as_uint(v);
    unsigned h = b & 0xFFFF0000u;
    hi = (ushort)(h >> 16);
    lo = (ushort)(__float_as_uint(v - __uint_as_float(h)) >> 16);
}

template <int CTRL>
__device__ __forceinline__ int dpp_i(int v) {
    return __builtin_amdgcn_update_dpp(0, v, CTRL, 0xF, 0xF, true);
}
template <int CTRL>
__device__ __forceinline__ float dpp_f(float x) {
    return __int_as_float(dpp_i<CTRL>(__float_as_int(x)));
}

__device__ __forceinline__ float red16(float x) {   // sum over 16-lane row
    x += dpp_f<0xB1>(x);    // lane^1
    x += dpp_f<0x4E>(x);    // lane^2
    x += dpp_f<0x141>(x);   // i <-> i^7 within 8-half
    x += dpp_f<0x140>(x);   // row mirror (pairs the two 8-halves)
    return x;
}
__device__ __forceinline__ float red8(float x) {    // sum over 8-lane group
    x += dpp_f<0xB1>(x);
    x += dpp_f<0x4E>(x);
    x += dpp_f<0x141>(x);
    return x;
}

// ---------------- sequential scan: 1 chain/block, 32 blocks ----------------
// M=2 (h-hat hi/lo rows) of the 16x16x32 MFMA; M-waste is free (MFMA pipe
// at ~36% in R9). 8 waves (2/SIMD); wave w owns N-tiles {2w,2w+1} with full
// K=256; B = Uhi/Ulo fragments (128 VGPR, persist). Pass2 reuses the SAME A
// (its even rows are identical -- R9's broadcast DPPs were dead code):
// y = P1[0](hi*Uhi) + P1[1](lo*Uhi) + P2[0](hi*Ulo). Cross-wave state: 1KB
// h-hat array + 8 float2 (ns,gs) partials, reduced by DPP butterflies.
// One barrier/step. State h lives in g==0 lanes' registers.
__global__ __launch_bounds__(512)
__attribute__((amdgpu_waves_per_eu(2, 2)))
void scan_kernel(
    const float* __restrict__ X,  const float* __restrict__ WX,
    const float* __restrict__ KS, const float* __restrict__ KVB,
    const ushort* __restrict__ Bf, const float* __restrict__ h0,
    const float* __restrict__ a_mem_p, float* __restrict__ Hf,
    float* __restrict__ HfOut)
{
    const int j    = blockIdx.x;       // chain 0..31
    const int tid  = threadIdx.x;
    const int w    = tid >> 6;         // wave 0..7
    const int lane = tid & 63;
    const int c15  = lane & 15;
    const int g    = lane >> 4;        // 0..3
    const bool own = (g == 0);         // lanes 0-15 own the state
    const bool evn = !(c15 & 1);

    __shared__ __align__(16) ushort arr[2][2][PADC];  // [buf][hi/lo][k]
    __shared__ float2 pred[2][8];                     // [buf][wave] (ns,gs)

    // ---- B fragments [tile][pass][kt] = 32 bf16x8 = 128 regs, persist ----
    bf16x8 bU[2][2][8];
#pragma unroll
    for (int tau = 0; tau < 2; ++tau)
#pragma unroll
        for (int p = 0; p < 2; ++p)
#pragma unroll
            for (int kt = 0; kt < 8; ++kt)
                bU[tau][p][kt] = *(const bf16x8*)
                    &Bf[(((size_t)(p*16 + 2*w + tau)*8 + kt)*64 + lane)*8];

    const float am = *a_mem_p;
    const int col0 = 32*w + c15, col1 = col0 + 16;

    // ---- init: state + consts in g==0 lanes; A buf0; pred0 ----
    float h[2] = {0.f, 0.f}, kv[2] = {0.f, 0.f}, wxc[2] = {0.f, 0.f};
    float gsi = 0.f;
    if (own) {
#pragma unroll
        for (int tau = 0; tau < 2; ++tau) {
            const int ct = tau ? col1 : col0;
            h[tau]   = h0[j*DD + ct];
            kv[tau]  = KVB[j*DD + ct];
            wxc[tau] = WX[ct];
            gsi += h[tau] * X[ct];
            ushort hh, hl; split_hilo(h[tau], hh, hl);
            arr[0][0][ct] = hh;  arr[0][1][ct] = hl;
        }
        gsi = red16(gsi);
    }
    if (lane == 0) pred[0][w] = make_float2(0.125f, gsi);  // ns sums to 1 -> inv=1
    float ks = KS[j];
    __syncthreads();

    bf16x8 a[8];
#pragma unroll
    for (int kt = 0; kt < 8; ++kt) a[kt] = (bf16x8){0,0,0,0,0,0,0,0};

    int cur = 0;
    for (int t = 0; t < N_SENT; ++t) {
        const int nxt = cur ^ 1;
        const int tn  = (t + 1 < N_SENT) ? t + 1 : t;

        // ---- prefetch t+1 operands (consumed ~whole step later) ----
        float xn0 = 0.f, xn1 = 0.f, wxn0 = 0.f, wxn1 = 0.f;
        if (own) {
            xn0  = X [tn*DD + col0];  xn1  = X [tn*DD + col1];
            wxn0 = WX[tn*DD + col0];  wxn1 = WX[tn*DD + col1];
        }
        const float ksn = KS[tn*NB + j];

        // ---- pred reduce (all lanes): inv + gate ----
        float2 pv = pred[cur][lane & 7];
        float rn = red8(pv.x), rg = red8(pv.y);
        const float inv  = rsqrtf(rn);
        const float gate = 1.f / (1.f + __expf(-(inv*rg + ks)));

        // ---- A fragments: rows 0(hi)/1(lo); other rows stay zero ----
        if (c15 < 2) {
#pragma unroll
            for (int kt = 0; kt < 8; ++kt)
                a[kt] = *(const bf16x8*)&arr[cur][c15][kt*32 + g*8];
        }

        // ---- MFMAs: 2 tiles x 2 passes, same A ----
        f32x4 q00 = {0,0,0,0}, q01 = {0,0,0,0};
        f32x4 q10 = {0,0,0,0}, q11 = {0,0,0,0};
#pragma unroll
        for (int kt = 0; kt < 8; ++kt) {
            q00 = __builtin_amdgcn_mfma_f32_16x16x32_bf16(a[kt], bU[0][0][kt], q00, 0, 0, 0);
            q10 = __builtin_amdgcn_mfma_f32_16x16x32_bf16(a[kt], bU[1][0][kt], q10, 0, 0, 0);
            q01 = __builtin_amdgcn_mfma_f32_16x16x32_bf16(a[kt], bU[0][1][kt], q01, 0, 0, 0);
            q11 = __builtin_amdgcn_mfma_f32_16x16x32_bf16(a[kt], bU[1][1][kt], q11, 0, 0, 0);
        }

        // ---- epilogue on g==0 lanes ----
        if (own) {
            float ns = 0.f, gs = 0.f;
#pragma unroll
            for (int tau = 0; tau < 2; ++tau) {
                const f32x4 P1 = tau ? q10 : q00;
                const f32x4 P2 = tau ? q11 : q01;
                const float xnt = tau ? xn1 : xn0;
                float y  = inv*(P1[0] + P1[1] + P2[0]) + kv[tau] + wxc[tau];
                float hs = (y >= 0.f) ? y : am*y;
                float hn = inv*h[tau] + gate*hs;
                h[tau] = hn;
                ns += hn*hn;  gs += hn*xnt;
                ushort hh, hl; split_hilo(hn, hh, hl);
                int hh2 = dpp_i<0xB1>((int)hh);
                int hl2 = dpp_i<0xB1>((int)hl);
                if (evn) {
                    uint ph = (uint)hh | ((uint)(ushort)hh2 << 16);
                    uint pl = (uint)hl | ((uint)(ushort)hl2 << 16);
                    const int ucol = 16*w + 8*tau + (c15 >> 1);
                    ((uint*)&arr[nxt][0][0])[ucol] = ph;
                    ((uint*)&arr[nxt][1][0])[ucol] = pl;
                }
            }
            ns = red16(ns);  gs = red16(gs);
            if (lane == 0) pred[nxt][w] = make_float2(ns, gs);
        }
        wxc[0] = wxn0;  wxc[1] = wxn1;  ks = ksn;
        cur = nxt;
        __syncthreads();
    }

    // ---- final normalize + output ----
    {
        float2 pv = pred[cur][lane & 7];
        const float inv = rsqrtf(red8(pv.x));
        if (own) {
#pragma unroll
            for (int tau = 0; tau < 2; ++tau) {
                const int ct = tau ? col1 : col0;
                const float v = h[tau] * inv;
                Hf[j*DD + ct]    = v;
                HfOut[j*DD + ct] = v;
            }
        }
    }
}

// ---------------- output module small part ----------------
__global__ __launch_bounds__(256) void out_small(
    const float* __restrict__ Qe, const float* __restrict__ Hfm,
    const float* __restrict__ Hw, const float* __restrict__ Hb,
    const float* __restrict__ a_out_p, float* __restrict__ Z)
{
    const int i = blockIdx.x, d = threadIdx.x;
    __shared__ float hsh[NB*DD];
    __shared__ float red[4];
    __shared__ float csh[NB];
    __shared__ float ush[DD];
#pragma unroll
    for (int jj = 0; jj < NB; ++jj) hsh[jj*DD + d] = Hfm[jj*DD + d];
    const float qd = Qe[i*DD + d];
    __syncthreads();
    float s2 = 0.f;
#pragma unroll
    for (int jj = 0; jj < NB; ++jj) { float h = hsh[jj*DD + d]; s2 += h*h; }
    for (int jj = 0; jj < NB; ++jj) {
        float p = qd * hsh[jj*DD + d];
        float m = p;
#pragma unroll
        for (int o = 32; o; o >>= 1) m = fmaxf(m, __shfl_xor(m, o));
        if ((d & 63) == 0) red[d >> 6] = m;
        __syncthreads();
        m = fmaxf(fmaxf(red[0], red[1]), fmaxf(red[2], red[3]));
        __syncthreads();
        float e = expf(p - m);
#pragma unroll
        for (int o = 32; o; o >>= 1) e += __shfl_xor(e, o);
        if ((d & 63) == 0) red[d >> 6] = e;
        __syncthreads();
        if (d == 0) csh[jj] = m + logf(red[0] + red[1] + red[2] + red[3]);
        __syncthreads();
    }
    float u = qd * s2;
#pragma unroll
    for (int jj = 0; jj < NB; ++jj) u -= csh[jj] * hsh[jj*DD + d];
    ush[d] = u;
    __syncthreads();
    float acc = qd + Hb[d];
    const float4* hwr = (const float4*)&Hw[d*DD];
    const float4* up  = (const float4*)ush;
#pragma unroll 8
    for (int k4 = 0; k4 < 64; ++k4) {
        float4 w = hwr[k4], uu = up[k4];
        acc += w.x*uu.x + w.y*uu.y + w.z*uu.z + w.w*uu.w;
    }
    const float ao = *a_out_p;
    Z[i*DD + d] = (acc >= 0.f) ? acc : ao * acc;
}

// ---------------- big GEMM: Y = Z @ Rw^T + Rb ----------------
__global__ __launch_bounds__(256) void out_gemm(
    const float* __restrict__ Z, const float* __restrict__ Rw,
    const float* __restrict__ Rb, float* __restrict__ Y)
{
    const int vt  = blockIdx.x * 64;
    const int tid = threadIdx.x;
    __shared__ float rw_sh[64*DD];
    __shared__ float z_sh[64*DD];
#pragma unroll
    for (int it = 0; it < 16; ++it) {
        int f = tid + it*256;
        int row = f >> 6, c = f & 63;
        float4 v = *(const float4*)&Rw[(size_t)(vt + row)*DD + 4*c];
        int u = c ^ ((row >> 2) & 7);
        *(float4*)&rw_sh[row*DD + 4*u] = v;
    }
    const int vg = tid & 15;
    const int ig = tid >> 4;
    const float4 rb4 = *(const float4*)&Rb[vt + vg*4];

    for (int ic = 0; ic < 2; ++ic) {
        const int i0 = ic * 64;
        __syncthreads();
#pragma unroll
        for (int it = 0; it < 16; ++it) {
            int f = tid + it*256;
            int row = f >> 6, c = f & 63;
            float4 v = *(const float4*)&Z[(i0 + row)*DD + 4*c];
            int u = c ^ ((row >> 2) & 7);
            *(float4*)&z_sh[row*DD + 4*u] = v;
        }
        __syncthreads();
        float acc[4][4];
#pragma unroll
        for (int b = 0; b < 4; ++b)
#pragma unroll
            for (int a = 0; a < 4; ++a) acc[b][a] = 0.f;
#pragma unroll 2
        for (int kc = 0; kc < 64; ++kc) {
            float4 ra[4], zb[4];
            const int ur = (kc ^ (vg & 7)) * 4;
            const int uz = (kc ^ (ig & 7)) * 4;
#pragma unroll
            for (int a = 0; a < 4; ++a) ra[a] = *(const float4*)&rw_sh[(vg*4 + a)*DD + ur];
#pragma unroll
            for (int b = 0; b < 4; ++b) zb[b] = *(const float4*)&z_sh[(ig*4 + b)*DD + uz];
#pragma unroll
            for (int b = 0; b < 4; ++b)
#pragma unroll
                for (int a = 0; a < 4; ++a)
                    acc[b][a] += zb[b].x*ra[a].x + zb[b].y*ra[a].y
                               + zb[b].z*ra[a].z + zb[b].w*ra[a].w;
        }
#pragma unroll
        for (int b = 0; b < 4; ++b) {
            int i = i0 + ig*4 + b;
            float4 o;
            o.x = acc[b][0] + rb4.x; o.y = acc[b][1] + rb4.y;
            o.z = acc[b][2] + rb4.z; o.w = acc[b][3] + rb4.w;
            *(float4*)&Y[(size_t)i*VOCAB + vt + vg*4] = o;
        }
    }
}

extern "C" void kernel_launch(void* const* d_in, const int* in_sizes, int n_in,
                              void* d_out, int out_size, void* d_ws, size_t ws_size,
                              hipStream_t stream)
{
    (void)in_sizes; (void)n_in; (void)out_size; (void)ws_size;
    const int*   inputs  = (const int*)  d_in[0];
    const int*   query   = (const int*)  d_in[1];
    const float* h0      = (const float*)d_in[2];
    const float* emb     = (const float*)d_in[3];
    const float* f_story = (const float*)d_in[4];
    const float* f_query = (const float*)d_in[5];
    const float* U       = (const float*)d_in[6];
    const float* V       = (const float*)d_in[7];
    const float* W       = (const float*)d_in[8];
    const float* bias    = (const float*)d_in[9];
    const float* keys    = (const float*)d_in[10];
    const float* a_mem   = (const float*)d_in[11];
    const float* Hw      = (const float*)d_in[12];
    const float* Hb      = (const float*)d_in[13];
    const float* Rw      = (const float*)d_in[14];
    const float* Rb      = (const float*)d_in[15];
    const float* a_out   = (const float*)d_in[16];

    float* ws  = (float*)d_ws;
    float* X   = ws + WS_X;
    float* WX  = ws + WS_WX;
    float* Qe  = ws + WS_Q;
    float* KS  = ws + WS_KS;
    float* KVB = ws + WS_KVB;
    float* Hf  = ws + WS_HF;
    float* Z   = ws + WS_Z;
    ushort* Bf = (ushort*)(ws + WS_BF);

    float* Y     = (float*)d_out;
    float* HfOut = Y + (size_t)NQ * VOCAB;

    encode_story<<<N_SENT, 256, 0, stream>>>(inputs, emb, f_story, X);
    encode_query<<<NQ,    256, 0, stream>>>(query,  emb, f_query, Qe);
    wx_ks      <<<N_SENT, 256, 0, stream>>>(X, W, keys, WX, KS);
    kvb_kernel <<<NB,     256, 0, stream>>>(keys, V, bias, KVB);
    prep_ufrag <<<256,     64, 0, stream>>>(U, Bf);
    scan_kernel<<<NB,     512, 0, stream>>>(X, WX, KS, KVB, Bf, h0, a_mem, Hf, HfOut);
    out_small  <<<NQ,     256, 0, stream>>>(Qe, Hf, Hw, Hb, a_out, Z);
    out_gemm   <<<VOCAB/64, 256, 0, stream>>>(Z, Rw, Rb, Y);
}